// Round 9
// baseline (377.867 us; speedup 1.0000x reference)
//
#include <hip/hip_runtime.h>
#include <hip/hip_bf16.h>

typedef float  f32x4 __attribute__((ext_vector_type(4)));
typedef short  s16x8 __attribute__((ext_vector_type(8)));

#define MEMH   256        // mem_dim
#define MSGD   512        // msg_dim
#define G3     768        // 3*H
#define W_IH_ELEMS (G3*MSGD)        // 393216
#define W_HH_ELEMS (G3*MEMH)        // 196608
#define W_TOT_ELEMS (W_IH_ELEMS + W_HH_ELEMS)  // 589824
#define W_BYTES    ((size_t)W_TOT_ELEMS * 2)   // 1179648

#define BM     32         // rows per GRU block
#define NTHR   1024       // 16 waves: 0-7 GRU, 8-15 copy
#define AM_OFF 0          // A_msg: 32x512 bf16, pitch 1024 B -> 32768 B
#define AH_OFF 32768      // A_h:   32x256 bf16, pitch 512 B  -> 16384 B
#define PART_OFF 49152    // part[32][8][2] f32 -> 2048 B
#define CNT_OFF  51200    // soft-barrier counter
#define LDS_BYTES 51264

static __device__ __forceinline__ short f2bf(float x) {
    __hip_bfloat16 b = __float2bfloat16(x);
    return __builtin_bit_cast(short, b);
}
static __device__ __forceinline__ float bf2f(short s) {
    unsigned int u = ((unsigned int)(unsigned short)s) << 16;
    return __builtin_bit_cast(float, u);
}
static __device__ __forceinline__ float sigf(float x) {
    return 1.f / (1.f + __expf(-x));
}
static __device__ __forceinline__ float tanh_fast(float x) {
    float e = __expf(-2.f * fabsf(x));
    float t = (1.f - e) / (1.f + e);
    return copysignf(t, x);
}
static __device__ __forceinline__ f32x4 ntload4(const float* p) {
    return __builtin_nontemporal_load((const f32x4*)p);
}
static __device__ __forceinline__ void ntstore4(float* p, f32x4 v) {
    __builtin_nontemporal_store(v, (f32x4*)p);
}

// ------------------------------------------------- full copy kernel (fallback)
__global__ void smu_copy_kernel(const float* __restrict__ mem,
                                const float* __restrict__ lu,
                                float* __restrict__ out_mem,
                                float* __restrict__ out_lu,
                                long n_mem4, long n_lu4) {
    long i = (long)blockIdx.x * blockDim.x + threadIdx.x;
    long stride = (long)gridDim.x * blockDim.x;
    long total = n_mem4 + n_lu4;
    for (; i < total; i += stride) {
        if (i < n_mem4) ntstore4(out_mem + i * 4, ntload4(mem + i * 4));
        else {
            long j = (i - n_mem4) * 4;
            ntstore4(out_lu + j, ntload4(lu + j));
        }
    }
}

// --------------------------------------------------- weight fp32->bf16 PACKED fragment layout
// ih: frag (t in [0,48), k in [0,16)) at elem off (t*16+k)*512; within frag
// elem idx = l*8+e  ->  source row t*16+(l&15), col k*32+(l>>4)*8+e.
// hh: frag (t in [0,48), k in [0,8)) at W_IH_ELEMS + (t*8+k)*512, same inner map.
__global__ void smu_cvtw_kernel(const float* __restrict__ wih,
                                const float* __restrict__ whh,
                                short* __restrict__ o) {
    int i = blockIdx.x * blockDim.x + threadIdx.x;
    if (i >= W_TOT_ELEMS) return;
    if (i < W_IH_ELEMS) {
        int f = i >> 9, r = i & 511, l = r >> 3, e = r & 7;
        int t = f >> 4, k = f & 15;
        int row = t * 16 + (l & 15), col = k * 32 + (l >> 4) * 8 + e;
        o[i] = f2bf(wih[row * MSGD + col]);
    } else {
        int j = i - W_IH_ELEMS;
        int f = j >> 9, r = j & 511, l = r >> 3, e = r & 7;
        int t = f >> 3, k = f & 7;
        int row = t * 16 + (l & 15), col = k * 32 + (l >> 4) * 8 + e;
        o[i] = f2bf(whh[row * MEMH + col]);
    }
}

// --------------------------------------------------- bitmap clear + set
__global__ void smu_clear_kernel(unsigned* __restrict__ p, int n) {
    int i = blockIdx.x * blockDim.x + threadIdx.x;
    if (i < n) p[i] = 0u;
}
__global__ void smu_bits_kernel(const int* __restrict__ ids,
                                unsigned* __restrict__ bm, int n) {
    int i = blockIdx.x * blockDim.x + threadIdx.x;
    if (i < n) {
        int id = ids[i];
        atomicOr(&bm[id >> 5], 1u << (id & 31));
    }
}

// ------------------------------------------------------------ B-frag loader
template<bool USE_WS>
static __device__ __forceinline__ s16x8 load_b(const float* __restrict__ Wf,
                                               const short* __restrict__ Wb,
                                               int t, int k, int ldk, int nkt, int lane) {
    if constexpr (USE_WS) {
        return *(const s16x8*)(Wb + ((size_t)(t * nkt + k) << 9) + lane * 8);
    } else {
        int row = t * 16 + (lane & 15);
        int col = k * 32 + (lane >> 4) * 8;
        f32x4 x = *(const f32x4*)(Wf + (size_t)row * ldk + col);
        f32x4 y = *(const f32x4*)(Wf + (size_t)row * ldk + col + 4);
        s16x8 s;
        s[0]=f2bf(x[0]); s[1]=f2bf(x[1]); s[2]=f2bf(x[2]); s[3]=f2bf(x[3]);
        s[4]=f2bf(y[0]); s[5]=f2bf(y[1]); s[6]=f2bf(y[2]); s[7]=f2bf(y[3]);
        return s;
    }
}

// --------------------------------------------------------------- fused kernel
// 1024-thread blocks, grid = 2048. Waves 0-7: GRU (BM=32 rows, wave w owns
// col-blocks {w, w+8}, all 3 gates -> lane-local gate math). Waves 8-15:
// 8-deep bitmap-skip copy of memory/last_update (8KB/wave in flight).
// One __syncthreads after cooperative A staging (all 16 waves). GRU-only LN
// sync via LDS partials + threadfence + LDS atomic counter + spin (copy waves
// never touch it -> no deadlock). Separate waves = separate vmcnt FIFOs:
// copy HBM latency never blocks GRU B-loads and vice versa.
template<bool USE_WS, bool FUSED>
__global__ __launch_bounds__(NTHR, 1)
void smu_fused_kernel(const int*   __restrict__ ids,
                      const float* __restrict__ msg,
                      const float* __restrict__ ts,
                      const float* __restrict__ memory,
                      const float* __restrict__ lu,
                      const float* __restrict__ W_ih,
                      const float* __restrict__ W_hh,
                      const float* __restrict__ b_ih,
                      const float* __restrict__ b_hh,
                      const float* __restrict__ gamma,
                      const float* __restrict__ beta,
                      const short* __restrict__ wsw,
                      const unsigned* __restrict__ bm,
                      float* __restrict__ out_mem,
                      float* __restrict__ out_lu,
                      long n_nodes) {
    __shared__ __align__(16) unsigned char lds[LDS_BYTES];
    const int tid = threadIdx.x;
    const int bid = blockIdx.x;
    const long base = (long)bid * BM;

    if (tid == 0) *(unsigned*)(lds + CNT_OFF) = 0u;

    // ---- cooperative A staging (all 16 waves)
    {
        const float* src = msg + base * MSGD;
        #pragma unroll
        for (int it = 0; it < 2; ++it) {
            int u = tid + NTHR * it;         // 0..2047 (32x512: 64 units/row)
            int row = u >> 6;
            f32x4 a = ntload4(src + u * 8);
            f32x4 b = ntload4(src + u * 8 + 4);
            s16x8 s;
            s[0]=f2bf(a[0]); s[1]=f2bf(a[1]); s[2]=f2bf(a[2]); s[3]=f2bf(a[3]);
            s[4]=f2bf(b[0]); s[5]=f2bf(b[1]); s[6]=f2bf(b[2]); s[7]=f2bf(b[3]);
            int byte = AM_OFF + ((u * 16) ^ ((row & 7) << 4));
            *(s16x8*)(lds + byte) = s;
        }
        {
            int u = tid;                     // 0..1023 (32x256: 32 units/row)
            int row = u >> 5;
            int c8  = u & 31;
            int id  = ids[base + row];
            const float* hs = memory + (size_t)id * MEMH + c8 * 8;
            f32x4 a = ntload4(hs);
            f32x4 b = ntload4(hs + 4);
            s16x8 s;
            s[0]=f2bf(a[0]); s[1]=f2bf(a[1]); s[2]=f2bf(a[2]); s[3]=f2bf(a[3]);
            s[4]=f2bf(b[0]); s[5]=f2bf(b[1]); s[6]=f2bf(b[2]); s[7]=f2bf(b[3]);
            int byte = AH_OFF + ((u * 16) ^ ((row & 7) << 4));
            *(s16x8*)(lds + byte) = s;
        }
    }
    __syncthreads();   // the ONLY block-wide barrier

    if (tid >= 512) {
        // ================= COPY role (waves 8..15) =================
        if constexpr (FUSED) {
            const long nu     = n_nodes * (MEMH / 4);       // 16B units
            const long stride = (long)gridDim.x * 512;
            const long i0     = (long)bid * 512 + (tid - 512);

            for (long i = i0; i < nu; i += stride * 8) {
                f32x4 v[8];
                bool  f[8];
                #pragma unroll
                for (int j = 0; j < 8; ++j) {
                    long u = i + stride * j;
                    f[j] = false;
                    if (u < nu) {
                        long r = u >> 6;
                        f[j] = !((bm[r >> 5] >> (r & 31)) & 1u);
                        if (f[j]) v[j] = ntload4(memory + u * 4);
                    }
                }
                #pragma unroll
                for (int j = 0; j < 8; ++j) {
                    long u = i + stride * j;
                    if (f[j]) ntstore4(out_mem + u * 4, v[j]);
                }
            }
            for (long i = i0; i < n_nodes; i += stride) {
                if (!((bm[i >> 5] >> (i & 31)) & 1u)) {
                    float v = __builtin_nontemporal_load(lu + i);
                    __builtin_nontemporal_store(v, out_lu + i);
                }
            }
        }
        return;
    }

    // ================= GRU role (waves 0..7) =================
    const int lane = tid & 63;
    const int w    = tid >> 6;              // 0..7
    const int lr   = lane & 15;
    const int lk8  = (lane >> 4) * 8;
    const int sw   = (lr & 7) << 4;
    const short* Wi = wsw;
    const short* Wh = wsw + W_IH_ELEMS;

    // tile i (0..5): cbi = i/3, g = i%3, t = w + 8*cbi + 16*g
    f32x4 rz[2][2][2] = {};   // [m][cbi][g<2]: r,z sums (both GEMMs)
    f32x4 gin[2][2]   = {};   // [m][cbi]: gi_n
    f32x4 ghn[2][2]   = {};   // [m][cbi]: gh_n

    // ---- GEMM 1: msg @ W_ih^T  (K=512, 16 ktiles, depth-2 B prefetch)
    {
        s16x8 b[2][6];
        #pragma unroll
        for (int i = 0; i < 6; ++i)
            b[0][i] = load_b<USE_WS>(W_ih, Wi, w + 8*(i/3) + 16*(i%3), 0, MSGD, 16, lane);
        #pragma unroll
        for (int i = 0; i < 6; ++i)
            b[1][i] = load_b<USE_WS>(W_ih, Wi, w + 8*(i/3) + 16*(i%3), 1, MSGD, 16, lane);
        #pragma unroll
        for (int k = 0; k < 16; ++k) {
            const int cb = (k * 32 + lk8) * 2;
            #pragma unroll
            for (int m = 0; m < 2; ++m) {
                s16x8 a = *(const s16x8*)(lds + AM_OFF + (((m*16 + lr) * 1024 + cb) ^ sw));
                #pragma unroll
                for (int ci = 0; ci < 2; ++ci) {
                    rz[m][ci][0] = __builtin_amdgcn_mfma_f32_16x16x32_bf16(a, b[k & 1][ci*3+0], rz[m][ci][0], 0, 0, 0);
                    rz[m][ci][1] = __builtin_amdgcn_mfma_f32_16x16x32_bf16(a, b[k & 1][ci*3+1], rz[m][ci][1], 0, 0, 0);
                    gin[m][ci]   = __builtin_amdgcn_mfma_f32_16x16x32_bf16(a, b[k & 1][ci*3+2], gin[m][ci],   0, 0, 0);
                }
            }
            if (k < 14) {
                #pragma unroll
                for (int i = 0; i < 6; ++i)
                    b[k & 1][i] = load_b<USE_WS>(W_ih, Wi, w + 8*(i/3) + 16*(i%3), k + 2, MSGD, 16, lane);
            }
        }
    }
    // ---- GEMM 2: h @ W_hh^T  (K=256, 8 ktiles)
    {
        s16x8 b[2][6];
        #pragma unroll
        for (int i = 0; i < 6; ++i)
            b[0][i] = load_b<USE_WS>(W_hh, Wh, w + 8*(i/3) + 16*(i%3), 0, MEMH, 8, lane);
        #pragma unroll
        for (int i = 0; i < 6; ++i)
            b[1][i] = load_b<USE_WS>(W_hh, Wh, w + 8*(i/3) + 16*(i%3), 1, MEMH, 8, lane);
        #pragma unroll
        for (int k = 0; k < 8; ++k) {
            const int cb = (k * 32 + lk8) * 2;
            #pragma unroll
            for (int m = 0; m < 2; ++m) {
                s16x8 a = *(const s16x8*)(lds + AH_OFF + (((m*16 + lr) * 512 + cb) ^ sw));
                #pragma unroll
                for (int ci = 0; ci < 2; ++ci) {
                    rz[m][ci][0] = __builtin_amdgcn_mfma_f32_16x16x32_bf16(a, b[k & 1][ci*3+0], rz[m][ci][0], 0, 0, 0);
                    rz[m][ci][1] = __builtin_amdgcn_mfma_f32_16x16x32_bf16(a, b[k & 1][ci*3+1], rz[m][ci][1], 0, 0, 0);
                    ghn[m][ci]   = __builtin_amdgcn_mfma_f32_16x16x32_bf16(a, b[k & 1][ci*3+2], ghn[m][ci],   0, 0, 0);
                }
            }
            if (k < 6) {
                #pragma unroll
                for (int i = 0; i < 6; ++i)
                    b[k & 1][i] = load_b<USE_WS>(W_hh, Wh, w + 8*(i/3) + 16*(i%3), k + 2, MEMH, 8, lane);
            }
        }
    }

    // ---- gate epilogue in registers (A_h LDS intact)
    const int lq = (lane >> 4);              // 0..3
    f32x4 o_[2][2];                          // [m][cbi]
    {
        #pragma unroll
        for (int ci = 0; ci < 2; ++ci) {
            const int j = (w + 8*ci) * 16 + lr;
            const float br = b_ih[j]       + b_hh[j];
            const float bz = b_ih[256 + j] + b_hh[256 + j];
            const float bihn = b_ih[512 + j], bhhn = b_hh[512 + j];
            #pragma unroll
            for (int m = 0; m < 2; ++m) {
                #pragma unroll
                for (int q = 0; q < 4; ++q) {
                    int row = m * 16 + lq * 4 + q;
                    float r = sigf(rz[m][ci][0][q] + br);
                    float z = sigf(rz[m][ci][1][q] + bz);
                    float n = tanh_fast(gin[m][ci][q] + bihn + r * (ghn[m][ci][q] + bhhn));
                    float hv = bf2f(*(const short*)(lds + AH_OFF + ((row * 512 + j * 2) ^ ((row & 7) << 4))));
                    o_[m][ci][q] = (1.f - z) * n + z * hv;
                }
            }
        }
    }

    // ---- per-wave LN partials (sum over this wave's 32 cols per row)
    {
        float* part = (float*)(lds + PART_OFF);
        #pragma unroll
        for (int m = 0; m < 2; ++m) {
            #pragma unroll
            for (int q = 0; q < 4; ++q) {
                float v0 = o_[m][0][q], v1 = o_[m][1][q];
                float s1 = v0 + v1;
                float s2 = v0 * v0 + v1 * v1;
                #pragma unroll
                for (int mk = 1; mk < 16; mk <<= 1) {
                    s1 += __shfl_xor(s1, mk);
                    s2 += __shfl_xor(s2, mk);
                }
                if (lr == 0) {
                    int row = m * 16 + lq * 4 + q;
                    part[(row * 8 + w) * 2]     = s1;
                    part[(row * 8 + w) * 2 + 1] = s2;
                }
            }
        }
    }

    // ---- GRU-waves-only soft barrier (copy waves never reach here)
    __threadfence_block();
    if (lane == 0) atomicAdd((unsigned*)(lds + CNT_OFF), 1u);
    {
        volatile unsigned* cp = (volatile unsigned*)(lds + CNT_OFF);
        while (*cp < 8u) __builtin_amdgcn_s_sleep(2);
    }
    __threadfence_block();

    // ---- per-lane row stats (redundant across lanes; avoids 2nd sync)
    float mu_[2][4], inv_[2][4];
    {
        const float* part = (const float*)(lds + PART_OFF);
        #pragma unroll
        for (int m = 0; m < 2; ++m) {
            #pragma unroll
            for (int q = 0; q < 4; ++q) {
                int row = m * 16 + lq * 4 + q;
                float s1 = 0.f, s2 = 0.f;
                #pragma unroll
                for (int i = 0; i < 8; ++i) {
                    s1 += part[(row * 8 + i) * 2];
                    s2 += part[(row * 8 + i) * 2 + 1];
                }
                float mu  = s1 * (1.f / 256.f);
                float var = fmaxf(s2 * (1.f / 256.f) - mu * mu, 0.f);
                mu_[m][q]  = mu;
                inv_[m][q] = rsqrtf(var + 1e-5f);
            }
        }
    }

    // ---- normalize + scatter
    {
        #pragma unroll
        for (int ci = 0; ci < 2; ++ci) {
            const int j = (w + 8*ci) * 16 + lr;
            const float ga = gamma[j], be = beta[j];
            #pragma unroll
            for (int m = 0; m < 2; ++m) {
                #pragma unroll
                for (int q = 0; q < 4; ++q) {
                    int row = m * 16 + lq * 4 + q;
                    int id = ids[base + row];
                    float y = (o_[m][ci][q] - mu_[m][q]) * inv_[m][q] * ga + be;
                    __builtin_nontemporal_store(y, out_mem + (size_t)id * MEMH + j);
                }
            }
        }
        if (w == 0 && lane < 32) {
            int id = ids[base + lane];
            __builtin_nontemporal_store(ts[base + lane], out_lu + id);
        }
    }
}

// ------------------------------------------------------------------- launcher
extern "C" void kernel_launch(void* const* d_in, const int* in_sizes, int n_in,
                              void* d_out, int out_size, void* d_ws, size_t ws_size,
                              hipStream_t stream) {
    (void)n_in; (void)out_size;
    const int*   ids = (const int*)  d_in[0];
    const float* msg = (const float*)d_in[1];
    const float* ts  = (const float*)d_in[2];
    const float* mem = (const float*)d_in[3];
    const float* lu  = (const float*)d_in[4];
    const float* Wih = (const float*)d_in[5];
    const float* Whh = (const float*)d_in[6];
    const float* bih = (const float*)d_in[7];
    const float* bhh = (const float*)d_in[8];
    const float* gam = (const float*)d_in[9];
    const float* bet = (const float*)d_in[10];

    const int  n_upd   = in_sizes[0];                 // 65536
    const long n_nodes = (long)in_sizes[3] / MEMH;    // 500000

    float* out_mem = (float*)d_out;
    float* out_lu  = out_mem + (size_t)n_nodes * MEMH;

    const int    bm_words     = (int)((n_nodes + 31) / 32) + 4;   // padded
    const size_t bm_bytes_pad = (size_t)bm_words * 4;
    const bool ws_w  = (d_ws != nullptr) && (ws_size >= W_BYTES);
    const bool ws_bm = (d_ws != nullptr) && (ws_size >= W_BYTES + bm_bytes_pad);

    short*    wsw = (short*)d_ws;
    unsigned* bm  = (unsigned*)((char*)d_ws + W_BYTES);

    const int grid = n_upd / BM;   // 65536/32 = 2048

    if (ws_w) {
        smu_cvtw_kernel<<<(W_TOT_ELEMS + 255) / 256, 256, 0, stream>>>(Wih, Whh, wsw);
    }

    if (ws_bm) {
        smu_clear_kernel<<<(bm_words + 255) / 256, 256, 0, stream>>>(bm, bm_words);
        smu_bits_kernel<<<(n_upd + 255) / 256, 256, 0, stream>>>(ids, bm, n_upd);
        // single dispatch: each block = 8 GRU waves + 8 copy waves
        smu_fused_kernel<true, true><<<grid, NTHR, 0, stream>>>(
            ids, msg, ts, mem, lu, Wih, Whh, bih, bhh, gam, bet,
            wsw, bm, out_mem, out_lu, n_nodes);
    } else {
        // fallback: full copy first, then GRU-only (copy waves exit early)
        long n_mem4 = n_nodes * (MEMH / 4);
        long n_lu4  = n_nodes / 4;
        smu_copy_kernel<<<2048, 256, 0, stream>>>(mem, lu, out_mem, out_lu, n_mem4, n_lu4);
        if (ws_w) {
            smu_fused_kernel<true, false><<<grid, NTHR, 0, stream>>>(
                ids, msg, ts, mem, lu, Wih, Whh, bih, bhh, gam, bet,
                wsw, nullptr, out_mem, out_lu, n_nodes);
        } else {
            smu_fused_kernel<false, false><<<grid, NTHR, 0, stream>>>(
                ids, msg, ts, mem, lu, Wih, Whh, bih, bhh, gam, bet,
                nullptr, nullptr, out_mem, out_lu, n_nodes);
        }
    }
}

// Round 10
// 341.258 us; speedup vs baseline: 1.1073x; 1.1073x over previous
//
#include <hip/hip_runtime.h>
#include <hip/hip_bf16.h>

typedef float  f32x4 __attribute__((ext_vector_type(4)));
typedef short  s16x8 __attribute__((ext_vector_type(8)));

#define MEMH   256        // mem_dim
#define MSGD   512        // msg_dim
#define G3     768        // 3*H
#define W_IH_ELEMS (G3*MSGD)        // 393216
#define W_HH_ELEMS (G3*MEMH)        // 196608
#define W_TOT_ELEMS (W_IH_ELEMS + W_HH_ELEMS)  // 589824
#define W_BYTES    ((size_t)W_TOT_ELEMS * 2)   // 1179648

#define BM     32         // rows per GRU block
#define NTHR   512        // 8 waves
#define AM_OFF 0          // A_msg: 32x512 bf16, pitch 1024 B -> 32768 B
#define AH_OFF 32768      // A_h:   32x256 bf16, pitch 512 B  -> 16384 B
#define PART_OFF 49152    // part[32][8][2] f32 -> 2048 B
#define LDS_BYTES 51200   // x2 blocks = 102400 <= 160K -> 2 blocks/CU

static __device__ __forceinline__ short f2bf(float x) {
    __hip_bfloat16 b = __float2bfloat16(x);
    return __builtin_bit_cast(short, b);
}
static __device__ __forceinline__ float bf2f(short s) {
    unsigned int u = ((unsigned int)(unsigned short)s) << 16;
    return __builtin_bit_cast(float, u);
}
static __device__ __forceinline__ float sigf(float x) {
    return 1.f / (1.f + __expf(-x));
}
static __device__ __forceinline__ float tanh_fast(float x) {
    float e = __expf(-2.f * fabsf(x));
    float t = (1.f - e) / (1.f + e);
    return copysignf(t, x);
}
static __device__ __forceinline__ f32x4 ntload4(const float* p) {
    return __builtin_nontemporal_load((const f32x4*)p);
}
static __device__ __forceinline__ void ntstore4(float* p, f32x4 v) {
    __builtin_nontemporal_store(v, (f32x4*)p);
}

// ------------------------------------------------- full copy kernel (fallback)
__global__ void smu_copy_kernel(const float* __restrict__ mem,
                                const float* __restrict__ lu,
                                float* __restrict__ out_mem,
                                float* __restrict__ out_lu,
                                long n_mem4, long n_lu4) {
    long i = (long)blockIdx.x * blockDim.x + threadIdx.x;
    long stride = (long)gridDim.x * blockDim.x;
    long total = n_mem4 + n_lu4;
    for (; i < total; i += stride) {
        if (i < n_mem4) ntstore4(out_mem + i * 4, ntload4(mem + i * 4));
        else {
            long j = (i - n_mem4) * 4;
            ntstore4(out_lu + j, ntload4(lu + j));
        }
    }
}

// ---------------------------------------- bitmap-skip copy (round-1 shape)
// One 16B unit per thread per iteration; a wave's 64 lanes = exactly one
// 1KB memory row -> the bitmap branch is wave-uniform. 2048x256 grid (the
// config that measured ~6 TB/s in round 1).
__global__ __launch_bounds__(256)
void smu_copy_skip_kernel(const float* __restrict__ mem,
                          const float* __restrict__ lu,
                          const unsigned* __restrict__ bm,
                          float* __restrict__ out_mem,
                          float* __restrict__ out_lu,
                          long n_nodes) {
    const long nu = n_nodes * (MEMH / 4);                 // 16B units
    const long stride = (long)gridDim.x * blockDim.x;
    const long i0 = (long)blockIdx.x * blockDim.x + threadIdx.x;

    for (long i = i0; i < nu; i += stride) {
        long r = i >> 6;
        if (!((bm[r >> 5] >> (r & 31)) & 1u))
            ntstore4(out_mem + i * 4, ntload4(mem + i * 4));
    }
    for (long i = i0; i < n_nodes; i += stride) {
        if (!((bm[i >> 5] >> (i & 31)) & 1u)) {
            float v = __builtin_nontemporal_load(lu + i);
            __builtin_nontemporal_store(v, out_lu + i);
        }
    }
}

// --------------------------------------------------- weight fp32->bf16 PACKED fragment layout
// ih: frag (t in [0,48), k in [0,16)) at elem off (t*16+k)*512; within frag
// elem idx = l*8+e  ->  source row t*16+(l&15), col k*32+(l>>4)*8+e.
// hh: frag (t in [0,48), k in [0,8)) at W_IH_ELEMS + (t*8+k)*512, same inner map.
__global__ void smu_cvtw_kernel(const float* __restrict__ wih,
                                const float* __restrict__ whh,
                                short* __restrict__ o) {
    int i = blockIdx.x * blockDim.x + threadIdx.x;
    if (i >= W_TOT_ELEMS) return;
    if (i < W_IH_ELEMS) {
        int f = i >> 9, r = i & 511, l = r >> 3, e = r & 7;
        int t = f >> 4, k = f & 15;
        int row = t * 16 + (l & 15), col = k * 32 + (l >> 4) * 8 + e;
        o[i] = f2bf(wih[row * MSGD + col]);
    } else {
        int j = i - W_IH_ELEMS;
        int f = j >> 9, r = j & 511, l = r >> 3, e = r & 7;
        int t = f >> 3, k = f & 7;
        int row = t * 16 + (l & 15), col = k * 32 + (l >> 4) * 8 + e;
        o[i] = f2bf(whh[row * MEMH + col]);
    }
}

// --------------------------------------------------- bitmap clear + set
__global__ void smu_clear_kernel(unsigned* __restrict__ p, int n) {
    int i = blockIdx.x * blockDim.x + threadIdx.x;
    if (i < n) p[i] = 0u;
}
__global__ void smu_bits_kernel(const int* __restrict__ ids,
                                unsigned* __restrict__ bm, int n) {
    int i = blockIdx.x * blockDim.x + threadIdx.x;
    if (i < n) {
        int id = ids[i];
        atomicOr(&bm[id >> 5], 1u << (id & 31));
    }
}

// ------------------------------------------------------------ B-frag loader
template<bool USE_WS>
static __device__ __forceinline__ s16x8 load_b(const float* __restrict__ Wf,
                                               const short* __restrict__ Wb,
                                               int t, int k, int ldk, int nkt, int lane) {
    if constexpr (USE_WS) {
        return *(const s16x8*)(Wb + ((size_t)(t * nkt + k) << 9) + lane * 8);
    } else {
        int row = t * 16 + (lane & 15);
        int col = k * 32 + (lane >> 4) * 8;
        f32x4 x = *(const f32x4*)(Wf + (size_t)row * ldk + col);
        f32x4 y = *(const f32x4*)(Wf + (size_t)row * ldk + col + 4);
        s16x8 s;
        s[0]=f2bf(x[0]); s[1]=f2bf(x[1]); s[2]=f2bf(x[2]); s[3]=f2bf(x[3]);
        s[4]=f2bf(y[0]); s[5]=f2bf(y[1]); s[6]=f2bf(y[2]); s[7]=f2bf(y[3]);
        return s;
    }
}

// --------------------------------------------------------------- GRU kernel
// 512 threads (8 waves), BM=32 rows, ~50 KB LDS, __launch_bounds__(512,4)
// -> 2 blocks/CU (16 waves, 4/SIMD) of INDEPENDENT blocks: cross-block wave
// diversity hides the per-k-step L2 B-load latency that a single barrier-
// synced block cannot. Wave w owns col-blocks {w, w+8}, all 3 gates ->
// gate math is lane-local. LN via register outputs + LDS partials.
template<bool USE_WS>
__global__ __launch_bounds__(NTHR, 4)
void smu_gru_kernel(const int*   __restrict__ ids,
                    const float* __restrict__ msg,
                    const float* __restrict__ ts,
                    const float* __restrict__ memory,
                    const float* __restrict__ W_ih,
                    const float* __restrict__ W_hh,
                    const float* __restrict__ b_ih,
                    const float* __restrict__ b_hh,
                    const float* __restrict__ gamma,
                    const float* __restrict__ beta,
                    const short* __restrict__ wsw,
                    float* __restrict__ out_mem,
                    float* __restrict__ out_lu) {
    __shared__ __align__(16) unsigned char lds[LDS_BYTES];
    const int tid = threadIdx.x;
    const long base = (long)blockIdx.x * BM;

    // ---- stage A_msg: 32x512 f32 -> bf16 (2048 units, 4/thread)
    {
        const float* src = msg + base * MSGD;
        #pragma unroll
        for (int it = 0; it < 4; ++it) {
            int u = tid + NTHR * it;         // 0..2047, 64 units/row
            int row = u >> 6;
            f32x4 a = ntload4(src + u * 8);
            f32x4 b = ntload4(src + u * 8 + 4);
            s16x8 s;
            s[0]=f2bf(a[0]); s[1]=f2bf(a[1]); s[2]=f2bf(a[2]); s[3]=f2bf(a[3]);
            s[4]=f2bf(b[0]); s[5]=f2bf(b[1]); s[6]=f2bf(b[2]); s[7]=f2bf(b[3]);
            int byte = AM_OFF + ((u * 16) ^ ((row & 7) << 4));
            *(s16x8*)(lds + byte) = s;
        }
        // ---- stage A_h (gather): 32x256 (1024 units, 2/thread)
        #pragma unroll
        for (int it = 0; it < 2; ++it) {
            int u = tid + NTHR * it;         // 0..1023, 32 units/row
            int row = u >> 5;
            int c8  = u & 31;
            int id  = ids[base + row];
            const float* hs = memory + (size_t)id * MEMH + c8 * 8;
            f32x4 a = ntload4(hs);
            f32x4 b = ntload4(hs + 4);
            s16x8 s;
            s[0]=f2bf(a[0]); s[1]=f2bf(a[1]); s[2]=f2bf(a[2]); s[3]=f2bf(a[3]);
            s[4]=f2bf(b[0]); s[5]=f2bf(b[1]); s[6]=f2bf(b[2]); s[7]=f2bf(b[3]);
            int byte = AH_OFF + ((u * 16) ^ ((row & 7) << 4));
            *(s16x8*)(lds + byte) = s;
        }
    }
    __syncthreads();

    const int lane = tid & 63;
    const int w    = tid >> 6;              // 0..7
    const int lr   = lane & 15;
    const int lk8  = (lane >> 4) * 8;
    const int sw   = (lr & 7) << 4;
    const short* Wi = wsw;
    const short* Wh = wsw + W_IH_ELEMS;

    // tile i (0..5): cbi = i/3, g = i%3, t = w + 8*cbi + 16*g
    f32x4 rz[2][2][2] = {};   // [m][cbi][g<2]: r,z sums (both GEMMs)
    f32x4 gin[2][2]   = {};   // [m][cbi]: gi_n
    f32x4 ghn[2][2]   = {};   // [m][cbi]: gh_n

    // ---- GEMM 1: msg @ W_ih^T  (K=512, 16 ktiles, depth-2 B prefetch)
    {
        s16x8 b[2][6];
        #pragma unroll
        for (int i = 0; i < 6; ++i)
            b[0][i] = load_b<USE_WS>(W_ih, Wi, w + 8*(i/3) + 16*(i%3), 0, MSGD, 16, lane);
        #pragma unroll
        for (int i = 0; i < 6; ++i)
            b[1][i] = load_b<USE_WS>(W_ih, Wi, w + 8*(i/3) + 16*(i%3), 1, MSGD, 16, lane);
        #pragma unroll
        for (int k = 0; k < 16; ++k) {
            const int cb = (k * 32 + lk8) * 2;
            #pragma unroll
            for (int m = 0; m < 2; ++m) {
                s16x8 a = *(const s16x8*)(lds + AM_OFF + (((m*16 + lr) * 1024 + cb) ^ sw));
                #pragma unroll
                for (int ci = 0; ci < 2; ++ci) {
                    rz[m][ci][0] = __builtin_amdgcn_mfma_f32_16x16x32_bf16(a, b[k & 1][ci*3+0], rz[m][ci][0], 0, 0, 0);
                    rz[m][ci][1] = __builtin_amdgcn_mfma_f32_16x16x32_bf16(a, b[k & 1][ci*3+1], rz[m][ci][1], 0, 0, 0);
                    gin[m][ci]   = __builtin_amdgcn_mfma_f32_16x16x32_bf16(a, b[k & 1][ci*3+2], gin[m][ci],   0, 0, 0);
                }
            }
            if (k < 14) {
                #pragma unroll
                for (int i = 0; i < 6; ++i)
                    b[k & 1][i] = load_b<USE_WS>(W_ih, Wi, w + 8*(i/3) + 16*(i%3), k + 2, MSGD, 16, lane);
            }
        }
    }
    // ---- GEMM 2: h @ W_hh^T  (K=256, 8 ktiles)
    {
        s16x8 b[2][6];
        #pragma unroll
        for (int i = 0; i < 6; ++i)
            b[0][i] = load_b<USE_WS>(W_hh, Wh, w + 8*(i/3) + 16*(i%3), 0, MEMH, 8, lane);
        #pragma unroll
        for (int i = 0; i < 6; ++i)
            b[1][i] = load_b<USE_WS>(W_hh, Wh, w + 8*(i/3) + 16*(i%3), 1, MEMH, 8, lane);
        #pragma unroll
        for (int k = 0; k < 8; ++k) {
            const int cb = (k * 32 + lk8) * 2;
            #pragma unroll
            for (int m = 0; m < 2; ++m) {
                s16x8 a = *(const s16x8*)(lds + AH_OFF + (((m*16 + lr) * 512 + cb) ^ sw));
                #pragma unroll
                for (int ci = 0; ci < 2; ++ci) {
                    rz[m][ci][0] = __builtin_amdgcn_mfma_f32_16x16x32_bf16(a, b[k & 1][ci*3+0], rz[m][ci][0], 0, 0, 0);
                    rz[m][ci][1] = __builtin_amdgcn_mfma_f32_16x16x32_bf16(a, b[k & 1][ci*3+1], rz[m][ci][1], 0, 0, 0);
                    ghn[m][ci]   = __builtin_amdgcn_mfma_f32_16x16x32_bf16(a, b[k & 1][ci*3+2], ghn[m][ci],   0, 0, 0);
                }
            }
            if (k < 6) {
                #pragma unroll
                for (int i = 0; i < 6; ++i)
                    b[k & 1][i] = load_b<USE_WS>(W_hh, Wh, w + 8*(i/3) + 16*(i%3), k + 2, MEMH, 8, lane);
            }
        }
    }

    // ---- gate epilogue in registers (A_h LDS intact)
    const int lq = (lane >> 4);              // 0..3
    f32x4 o_[2][2];                          // [m][cbi]
    {
        #pragma unroll
        for (int ci = 0; ci < 2; ++ci) {
            const int j = (w + 8*ci) * 16 + lr;
            const float br = b_ih[j]       + b_hh[j];
            const float bz = b_ih[256 + j] + b_hh[256 + j];
            const float bihn = b_ih[512 + j], bhhn = b_hh[512 + j];
            #pragma unroll
            for (int m = 0; m < 2; ++m) {
                #pragma unroll
                for (int q = 0; q < 4; ++q) {
                    int row = m * 16 + lq * 4 + q;
                    float r = sigf(rz[m][ci][0][q] + br);
                    float z = sigf(rz[m][ci][1][q] + bz);
                    float n = tanh_fast(gin[m][ci][q] + bihn + r * (ghn[m][ci][q] + bhhn));
                    float hv = bf2f(*(const short*)(lds + AH_OFF + ((row * 512 + j * 2) ^ ((row & 7) << 4))));
                    o_[m][ci][q] = (1.f - z) * n + z * hv;
                }
            }
        }
    }

    // ---- per-wave LN partials (sum over this wave's 32 cols per row)
    {
        float* part = (float*)(lds + PART_OFF);
        #pragma unroll
        for (int m = 0; m < 2; ++m) {
            #pragma unroll
            for (int q = 0; q < 4; ++q) {
                float v0 = o_[m][0][q], v1 = o_[m][1][q];
                float s1 = v0 + v1;
                float s2 = v0 * v0 + v1 * v1;
                #pragma unroll
                for (int mk = 1; mk < 16; mk <<= 1) {
                    s1 += __shfl_xor(s1, mk);
                    s2 += __shfl_xor(s2, mk);
                }
                if (lr == 0) {
                    int row = m * 16 + lq * 4 + q;
                    part[(row * 8 + w) * 2]     = s1;
                    part[(row * 8 + w) * 2 + 1] = s2;
                }
            }
        }
    }
    __syncthreads();

    // ---- per-lane row stats (redundant across lanes; broadcast LDS reads)
    float mu_[2][4], inv_[2][4];
    {
        const float* part = (const float*)(lds + PART_OFF);
        #pragma unroll
        for (int m = 0; m < 2; ++m) {
            #pragma unroll
            for (int q = 0; q < 4; ++q) {
                int row = m * 16 + lq * 4 + q;
                float s1 = 0.f, s2 = 0.f;
                #pragma unroll
                for (int i = 0; i < 8; ++i) {
                    s1 += part[(row * 8 + i) * 2];
                    s2 += part[(row * 8 + i) * 2 + 1];
                }
                float mu  = s1 * (1.f / 256.f);
                float var = fmaxf(s2 * (1.f / 256.f) - mu * mu, 0.f);
                mu_[m][q]  = mu;
                inv_[m][q] = rsqrtf(var + 1e-5f);
            }
        }
    }

    // ---- normalize + scatter
    {
        #pragma unroll
        for (int ci = 0; ci < 2; ++ci) {
            const int j = (w + 8*ci) * 16 + lr;
            const float ga = gamma[j], be = beta[j];
            #pragma unroll
            for (int m = 0; m < 2; ++m) {
                #pragma unroll
                for (int q = 0; q < 4; ++q) {
                    int row = m * 16 + lq * 4 + q;
                    int id = ids[base + row];
                    float y = (o_[m][ci][q] - mu_[m][q]) * inv_[m][q] * ga + be;
                    __builtin_nontemporal_store(y, out_mem + (size_t)id * MEMH + j);
                }
            }
        }
        if (w == 0 && lane < 32) {
            int id = ids[base + lane];
            __builtin_nontemporal_store(ts[base + lane], out_lu + id);
        }
    }
}

// ------------------------------------------------------------------- launcher
extern "C" void kernel_launch(void* const* d_in, const int* in_sizes, int n_in,
                              void* d_out, int out_size, void* d_ws, size_t ws_size,
                              hipStream_t stream) {
    (void)n_in; (void)out_size;
    const int*   ids = (const int*)  d_in[0];
    const float* msg = (const float*)d_in[1];
    const float* ts  = (const float*)d_in[2];
    const float* mem = (const float*)d_in[3];
    const float* lu  = (const float*)d_in[4];
    const float* Wih = (const float*)d_in[5];
    const float* Whh = (const float*)d_in[6];
    const float* bih = (const float*)d_in[7];
    const float* bhh = (const float*)d_in[8];
    const float* gam = (const float*)d_in[9];
    const float* bet = (const float*)d_in[10];

    const int  n_upd   = in_sizes[0];                 // 65536
    const long n_nodes = (long)in_sizes[3] / MEMH;    // 500000

    float* out_mem = (float*)d_out;
    float* out_lu  = out_mem + (size_t)n_nodes * MEMH;

    const int    bm_words     = (int)((n_nodes + 31) / 32) + 4;   // padded
    const size_t bm_bytes_pad = (size_t)bm_words * 4;
    const bool ws_w  = (d_ws != nullptr) && (ws_size >= W_BYTES);
    const bool ws_bm = (d_ws != nullptr) && (ws_size >= W_BYTES + bm_bytes_pad);

    short*    wsw = (short*)d_ws;
    unsigned* bm  = (unsigned*)((char*)d_ws + W_BYTES);

    const int grid = n_upd / BM;   // 65536/32 = 2048

    if (ws_bm && ws_w) {
        // clear -> bits -> copy (bitmap-skipped, leaves memory L3-warm)
        // -> cvtw (weights L2-hot) -> gru
        smu_clear_kernel<<<(bm_words + 255) / 256, 256, 0, stream>>>(bm, bm_words);
        smu_bits_kernel<<<(n_upd + 255) / 256, 256, 0, stream>>>(ids, bm, n_upd);
        smu_copy_skip_kernel<<<2048, 256, 0, stream>>>(mem, lu, bm, out_mem, out_lu, n_nodes);
        smu_cvtw_kernel<<<(W_TOT_ELEMS + 255) / 256, 256, 0, stream>>>(Wih, Whh, wsw);
        smu_gru_kernel<true><<<grid, NTHR, 0, stream>>>(
            ids, msg, ts, mem, Wih, Whh, bih, bhh, gam, bet, wsw, out_mem, out_lu);
    } else {
        // fallback: full copy first, then GRU scatter overwrites updated rows
        long n_mem4 = n_nodes * (MEMH / 4);
        long n_lu4  = n_nodes / 4;
        smu_copy_kernel<<<2048, 256, 0, stream>>>(mem, lu, out_mem, out_lu, n_mem4, n_lu4);
        if (ws_w) {
            smu_cvtw_kernel<<<(W_TOT_ELEMS + 255) / 256, 256, 0, stream>>>(Wih, Whh, wsw);
            smu_gru_kernel<true><<<grid, NTHR, 0, stream>>>(
                ids, msg, ts, mem, Wih, Whh, bih, bhh, gam, bet, wsw, out_mem, out_lu);
        } else {
            smu_gru_kernel<false><<<grid, NTHR, 0, stream>>>(
                ids, msg, ts, mem, Wih, Whh, bih, bhh, gam, bet, nullptr, out_mem, out_lu);
        }
    }
}